// Round 3
// baseline (616.212 us; speedup 1.0000x reference)
//
#include <hip/hip_runtime.h>

#define B_   2
#define H_   16
#define HK_  4
#define G_   4
#define S_   2048
#define D_   128
#define I_   2048

#define BM   64           // S-rows per block (16 per wave)
#define BN   64           // I-cols per iter
#define TPB  256          // 4 waves
#define NIT  (I_/BN)      // 32

#define LDK  136          // Ks/Us row stride (f16): 128+8 pad

static constexpr float SCALE = 0.08838834764831845f;  // 1/sqrt(128)

typedef _Float16 h8v __attribute__((ext_vector_type(8)));
typedef _Float16 h4v __attribute__((ext_vector_type(4)));
typedef float    f4v __attribute__((ext_vector_type(4)));

#define KU_ELEMS (HK_ * I_ * D_)   // 1048576 per tensor

// ---------------- fused prologue: K,U -> f16 row-major; V -> f16 transposed ----------------
__global__ __launch_bounds__(256) void prep(const float* __restrict__ Kg,
                                            const float* __restrict__ Ug,
                                            const float* __restrict__ Vg,
                                            _Float16* __restrict__ Kh,
                                            _Float16* __restrict__ Uh,
                                            _Float16* __restrict__ Vt) {
    __shared__ _Float16 T[D_ * 72];
    const int bid = blockIdx.x;
    const int tid = threadIdx.x;
    if (bid < 1024) {
        const size_t off = ((size_t)(bid & 511) * 256 + tid) * 8;
        const float* src = (bid < 512) ? (Kg + off) : (Ug + off);
        _Float16*    dst = (bid < 512) ? (Kh + off) : (Uh + off);
        const float4 a = *(const float4*)src;
        const float4 c = *(const float4*)(src + 4);
        h8v v;
        v[0] = (_Float16)a.x; v[1] = (_Float16)a.y; v[2] = (_Float16)a.z; v[3] = (_Float16)a.w;
        v[4] = (_Float16)c.x; v[5] = (_Float16)c.y; v[6] = (_Float16)c.z; v[7] = (_Float16)c.w;
        *(h8v*)dst = v;
    } else {
        const int vb    = bid - 1024;        // 0..127
        const int kh    = vb >> 5;
        const int itile = vb & 31;
        const int i0    = itile * 64;
        {   // read 64 i-rows x 128 d, coalesced along d; scatter into T
            const int i = tid >> 2, dbase = (tid & 3) * 32;
            const float* vp = Vg + ((size_t)kh * I_ + (i0 + i)) * D_ + dbase;
#pragma unroll
            for (int j = 0; j < 32; j += 4) {
                const float4 x = *(const float4*)(vp + j);
                T[(dbase + j + 0) * 72 + i] = (_Float16)x.x;
                T[(dbase + j + 1) * 72 + i] = (_Float16)x.y;
                T[(dbase + j + 2) * 72 + i] = (_Float16)x.z;
                T[(dbase + j + 3) * 72 + i] = (_Float16)x.w;
            }
        }
        __syncthreads();
        {   // write d-rows, coalesced along i
            const int d = tid >> 1, ic = (tid & 1) * 32;
            _Float16* op = Vt + ((size_t)kh * D_ + d) * I_ + i0 + ic;
#pragma unroll
            for (int j = 0; j < 32; j += 8)
                *(h8v*)(op + j) = *(const h8v*)(&T[d * 72 + ic + j]);
        }
    }
}

// ---------------- main fused kernel ----------------
__global__ __launch_bounds__(TPB, 4) void flashmlp_kernel(
    const float* __restrict__ Qg,
    const _Float16* __restrict__ Kh,
    const _Float16* __restrict__ Uh,
    const _Float16* __restrict__ Vth,
    float* __restrict__ Og)
{
    // LDS: 2 * 64*136 f16 = 34816 B -> 4 blocks/CU (139 KB of 160)
    __shared__ _Float16 Ks[BN * LDK];
    __shared__ _Float16 Us[BN * LDK];

    // XCD swizzle: xcd = bid&7 -> kv-head = xcd>>1 (each XCD-pair owns one head's K/U/V in L2)
    const int bid = blockIdx.x;                 // 0..1023
    const int xcd = bid & 7;
    const int kh  = xcd >> 1;
    const int sub = ((bid >> 3) << 1) | (xcd & 1);   // 0..255 within head
    const int stile = sub & 31;                 // 32 S-tiles of 64
    const int bg    = sub >> 5;                 // 0..7
    const int b     = bg >> 2;
    const int g     = bg & 3;
    const int h     = kh * G_ + g;

    const int tid  = threadIdx.x;
    const int wave = tid >> 6;
    const int m16  = (tid & 63) & 15;
    const int qq   = (tid & 63) >> 4;

    const size_t qbase = ((size_t)(b * H_ + h) * S_ + (size_t)stile * BM) * D_;
    const size_t kub   = (size_t)kh * I_ * D_;
    const size_t vtb   = (size_t)kh * D_ * I_;   // Vt[d][i]

    // ---- Q fragments (B-operand of M^T), pre-scaled; 16 rows per wave, register-resident
    h8v qf[4];
    {
        const float* qp = Qg + qbase + (size_t)(wave * 16 + m16) * D_;
#pragma unroll
        for (int ks = 0; ks < 4; ++ks) {
            const float4 a = *(const float4*)(qp + ks * 32 + qq * 8);
            const float4 c = *(const float4*)(qp + ks * 32 + qq * 8 + 4);
            h8v v;
            v[0] = (_Float16)(a.x * SCALE); v[1] = (_Float16)(a.y * SCALE);
            v[2] = (_Float16)(a.z * SCALE); v[3] = (_Float16)(a.w * SCALE);
            v[4] = (_Float16)(c.x * SCALE); v[5] = (_Float16)(c.y * SCALE);
            v[6] = (_Float16)(c.z * SCALE); v[7] = (_Float16)(c.w * SCALE);
            qf[ks] = v;
        }
    }

    f4v acc[8];
#pragma unroll
    for (int dt = 0; dt < 8; ++dt) acc[dt] = f4v{0.f, 0.f, 0.f, 0.f};

    const int srow = tid >> 2;          // 0..63
    const int scol = (tid & 3) * 32;

    for (int it = 0; it < NIT; ++it) {
        const int i0 = it * BN;

        __syncthreads();   // previous tile's readers done

        // ---- JIT staging (transient regs; latency covered by other resident blocks)
        {
            const _Float16* kp = Kh + kub + (size_t)(i0 + srow) * D_ + scol;
            const _Float16* up = Uh + kub + (size_t)(i0 + srow) * D_ + scol;
            h8v kb[4], ub[4];
#pragma unroll
            for (int c = 0; c < 4; ++c) { kb[c] = *(const h8v*)(kp + c * 8); ub[c] = *(const h8v*)(up + c * 8); }
#pragma unroll
            for (int c = 0; c < 4; ++c) {
                *(h8v*)(&Ks[srow * LDK + scol + c * 8]) = kb[c];
                *(h8v*)(&Us[srow * LDK + scol + c * 8]) = ub[c];
            }
        }
        __syncthreads();

        // ---- M^T = K Q^T, N^T = U Q^T  (swapped operands; D[m=i][n=s])
        f4v am[4], an[4];
#pragma unroll
        for (int ct = 0; ct < 4; ++ct) { am[ct] = f4v{0.f,0.f,0.f,0.f}; an[ct] = f4v{0.f,0.f,0.f,0.f}; }
#pragma unroll
        for (int ct = 0; ct < 4; ++ct) {
#pragma unroll
            for (int ks = 0; ks < 4; ++ks) {
                const h8v kf = *(const h8v*)(&Ks[(ct * 16 + m16) * LDK + ks * 32 + qq * 8]);
                const h8v uf = *(const h8v*)(&Us[(ct * 16 + m16) * LDK + ks * 32 + qq * 8]);
                am[ct] = __builtin_amdgcn_mfma_f32_16x16x32_f16(kf, qf[ks], am[ct], 0, 0, 0);
                an[ct] = __builtin_amdgcn_mfma_f32_16x16x32_f16(uf, qf[ks], an[ct], 0, 0, 0);
            }
        }

        // ---- gate in registers: A^T tile is directly the 16x16x16 A-operand
        h4v ag[4];
#pragma unroll
        for (int ct = 0; ct < 4; ++ct)
#pragma unroll
            for (int r = 0; r < 4; ++r) {
                const float mv = am[ct][r];
                const float nv = an[ct][r];
                const float sg = __builtin_amdgcn_rcpf(1.f + __expf(-mv));
                ag[ct][r] = (_Float16)(mv * sg * nv);
            }

        // ---- O += A V; V B-frags from global, register double-buffered by ct-group
        const _Float16* vbase = Vth + vtb + i0 + qq * 4;
        h4v vfA[8], vfB[8];
#pragma unroll
        for (int dt = 0; dt < 8; ++dt)
            vfA[dt] = *(const h4v*)(vbase + (size_t)(dt * 16 + m16) * I_);
#pragma unroll
        for (int ct = 0; ct < 4; ++ct) {
            const h4v* cur = (ct & 1) ? vfB : vfA;
            h4v*       nxt = (ct & 1) ? vfA : vfB;
            if (ct < 3) {
#pragma unroll
                for (int dt = 0; dt < 8; ++dt)
                    nxt[dt] = *(const h4v*)(vbase + (size_t)(dt * 16 + m16) * I_ + (ct + 1) * 16);
            }
#pragma unroll
            for (int dt = 0; dt < 8; ++dt)
                acc[dt] = __builtin_amdgcn_mfma_f32_16x16x16f16(ag[ct], cur[dt], acc[dt], 0, 0, 0);
        }
    }

    // ---- epilogue: D[m=s][n=d], row = qq*4+r, col = m16
#pragma unroll
    for (int r = 0; r < 4; ++r) {
        const int row = stile * BM + wave * 16 + qq * 4 + r;
        float* op = Og + ((size_t)(b * H_ + h) * S_ + row) * D_;
#pragma unroll
        for (int dt = 0; dt < 8; ++dt)
            op[dt * 16 + m16] = acc[dt][r];
    }
}

extern "C" void kernel_launch(void* const* d_in, const int* in_sizes, int n_in,
                              void* d_out, int out_size, void* d_ws, size_t ws_size,
                              hipStream_t stream) {
    const float* Q = (const float*)d_in[0];
    const float* K = (const float*)d_in[1];
    const float* U = (const float*)d_in[2];
    const float* V = (const float*)d_in[3];
    float* out = (float*)d_out;

    _Float16* Kh  = (_Float16*)d_ws;
    _Float16* Uh  = Kh + KU_ELEMS;
    _Float16* Vth = Uh + KU_ELEMS;   // 6 MB total in d_ws

    prep<<<dim3(1152), dim3(256), 0, stream>>>(K, U, V, Kh, Uh, Vth);

    const int grid = (S_ / BM) * B_ * H_;   // 32 * 32 = 1024 blocks -> 4 blocks/CU
    flashmlp_kernel<<<dim3(grid), dim3(TPB), 0, stream>>>(Q, Kh, Uh, Vth, out);
}

// Round 5
// 389.988 us; speedup vs baseline: 1.5801x; 1.5801x over previous
//
#include <hip/hip_runtime.h>

#define B_   2
#define H_   16
#define HK_  4
#define G_   4
#define S_   2048
#define D_   128
#define I_   2048

#define BM   128          // S-rows per block (32 per wave, rt=2)
#define TPB  256          // 4 waves
#define NIT  32           // I tiles of 64

static constexpr float SCALE = 0.08838834764831845f;  // 1/sqrt(128)

typedef _Float16 h8v __attribute__((ext_vector_type(8)));
typedef _Float16 h4v __attribute__((ext_vector_type(4)));
typedef float    f4v __attribute__((ext_vector_type(4)));

#define FRAG_PER_KH (I_ * D_)   // 262144 f16 per kv-head per tensor

// ---------------- prologue: build fragment-ready Kf/Uf/Vf ----------------
// Kf/Uf chunk layout (per kh): [it(32)][ct(4)][ks(4)][lane(64)][8 f16]
//   lane(m16=l&15, qq=l>>4) holds K[i = it*64+ct*16+m16][d = ks*32+qq*8 .. +8]
//   == A-operand frag of mfma_f32_16x16x32_f16 for the M^T=K*Q^T product.
//   per-it span: 4*4*64*8 = 8192 f16.
// Vf chunk layout (per kh): [it(32)][p(2)][dt(8)][lane(64)][8 f16]
//   lane holds, for c2=0,1: V[i = it*64+(p*2+c2)*16+qq*4 .. +4][d = dt*16+m16]
//   == packed pair of B-operand frags of mfma_f32_16x16x16f16 for O=A*V.
//   per-it span: 2*8*64*8 = 8192 f16.
__global__ __launch_bounds__(256) void prep(const float* __restrict__ Kg,
                                            const float* __restrict__ Ug,
                                            const float* __restrict__ Vg,
                                            _Float16* __restrict__ Kf,
                                            _Float16* __restrict__ Uf,
                                            _Float16* __restrict__ Vf) {
    const int bid = blockIdx.x;
    const int tid = threadIdx.x;
    if (bid < 1024) {
        const int c   = (bid & 511) * 256 + tid;   // chunk id, [0, 131072)
        const int kh  = c >> 15;
        const int r   = c & 32767;
        const int it  = r >> 10;
        const int ct  = (r >> 8) & 3;
        const int ks  = (r >> 6) & 3;
        const int l   = r & 63;
        const int m16 = l & 15, qq = l >> 4;
        const int i   = it * 64 + ct * 16 + m16;
        const int d   = ks * 32 + qq * 8;
        const float* src = ((bid < 512) ? Kg : Ug) + (size_t)(kh * I_ + i) * D_ + d;
        const float4 a = *(const float4*)src;
        const float4 bb = *(const float4*)(src + 4);
        h8v v;
        v[0]=(_Float16)a.x;  v[1]=(_Float16)a.y;  v[2]=(_Float16)a.z;  v[3]=(_Float16)a.w;
        v[4]=(_Float16)bb.x; v[5]=(_Float16)bb.y; v[6]=(_Float16)bb.z; v[7]=(_Float16)bb.w;
        *(h8v*)(((bid < 512) ? Kf : Uf) + (size_t)c * 8) = v;
    } else {
        const int c   = (bid - 1024) * 256 + tid;  // [0, 131072)
        const int kh  = c >> 15;
        const int r   = c & 32767;
        const int it  = r >> 10;
        const int p   = (r >> 9) & 1;
        const int dt  = (r >> 6) & 7;
        const int l   = r & 63;
        const int m16 = l & 15, qq = l >> 4;
        const int d   = dt * 16 + m16;
        h8v v;
#pragma unroll
        for (int c2 = 0; c2 < 2; ++c2) {
            const int i = it * 64 + (p * 2 + c2) * 16 + qq * 4;
#pragma unroll
            for (int jj = 0; jj < 4; ++jj)
                v[c2 * 4 + jj] = (_Float16)Vg[(size_t)(kh * I_ + i + jj) * D_ + d];
        }
        *(h8v*)(Vf + (size_t)c * 8) = v;
    }
}

// ---------------- main fused kernel: no LDS, no __syncthreads ----------------
__global__ __launch_bounds__(TPB, 2) void flashmlp_kernel(
    const float* __restrict__ Qg,
    const _Float16* __restrict__ Kf,
    const _Float16* __restrict__ Uf,
    const _Float16* __restrict__ Vf,
    float* __restrict__ Og)
{
    // XCD swizzle: xcd = bid&7 -> kv-head = xcd>>1 (head's ~1.5MB f16 frags live in XCD L2)
    const int bid   = blockIdx.x;                 // 0..511
    const int xcd   = bid & 7;
    const int kh    = xcd >> 1;
    const int j     = ((bid >> 3) << 1) | (xcd & 1);
    const int stile = j & 15;
    const int bg    = j >> 4;
    const int b     = bg >> 2;
    const int g     = bg & 3;
    const int h     = kh * G_ + g;

    const int tid  = threadIdx.x;
    const int wave = tid >> 6;
    const int l    = tid & 63;
    const int m16  = l & 15;
    const int qq   = l >> 4;

    const size_t qbase = ((size_t)(b * H_ + h) * S_ + (size_t)stile * BM) * D_;

    // ---- Q fragments (B-operand of M^T), pre-scaled by 1/sqrt(D); 32 rows/wave
    h8v qf[2][4];
#pragma unroll
    for (int rt = 0; rt < 2; ++rt) {
        const float* qp = Qg + qbase + (size_t)(wave * 32 + rt * 16 + m16) * D_;
#pragma unroll
        for (int ks = 0; ks < 4; ++ks) {
            const float4 a = *(const float4*)(qp + ks * 32 + qq * 8);
            const float4 c = *(const float4*)(qp + ks * 32 + qq * 8 + 4);
            h8v v;
            v[0] = (_Float16)(a.x * SCALE); v[1] = (_Float16)(a.y * SCALE);
            v[2] = (_Float16)(a.z * SCALE); v[3] = (_Float16)(a.w * SCALE);
            v[4] = (_Float16)(c.x * SCALE); v[5] = (_Float16)(c.y * SCALE);
            v[6] = (_Float16)(c.z * SCALE); v[7] = (_Float16)(c.w * SCALE);
            qf[rt][ks] = v;
        }
    }

    f4v acc[2][8];
#pragma unroll
    for (int rt = 0; rt < 2; ++rt)
#pragma unroll
        for (int dt = 0; dt < 8; ++dt)
            acc[rt][dt] = f4v{0.f, 0.f, 0.f, 0.f};

    // wave-uniform frag bases + lane offset
    const _Float16* kb = Kf + (size_t)kh * FRAG_PER_KH + l * 8;
    const _Float16* ub = Uf + (size_t)kh * FRAG_PER_KH + l * 8;
    const _Float16* vb = Vf + (size_t)kh * FRAG_PER_KH + l * 8;

    for (int it = 0; it < NIT; ++it) {
        if ((it & 3) == 0) __builtin_amdgcn_s_barrier();   // loose convoy for L1 reuse

        const _Float16* kp = kb + (size_t)it * 8192;   // 16 chunks x 512 f16
        const _Float16* up = ub + (size_t)it * 8192;

        // ---- M^T = K Q^T, N^T = U Q^T (swapped operands; D[m=i][n=s])
        f4v am[2][4], an[2][4];
#pragma unroll
        for (int ct = 0; ct < 4; ++ct) {
            h8v kf[4], uf[4];
#pragma unroll
            for (int ks = 0; ks < 4; ++ks) {
                kf[ks] = *(const h8v*)(kp + (ct * 4 + ks) * 512);
                uf[ks] = *(const h8v*)(up + (ct * 4 + ks) * 512);
            }
#pragma unroll
            for (int rt = 0; rt < 2; ++rt) {
                am[rt][ct] = __builtin_amdgcn_mfma_f32_16x16x32_f16(kf[0], qf[rt][0], f4v{0.f,0.f,0.f,0.f}, 0, 0, 0);
                an[rt][ct] = __builtin_amdgcn_mfma_f32_16x16x32_f16(uf[0], qf[rt][0], f4v{0.f,0.f,0.f,0.f}, 0, 0, 0);
            }
#pragma unroll
            for (int ks = 1; ks < 4; ++ks)
#pragma unroll
                for (int rt = 0; rt < 2; ++rt) {
                    am[rt][ct] = __builtin_amdgcn_mfma_f32_16x16x32_f16(kf[ks], qf[rt][ks], am[rt][ct], 0, 0, 0);
                    an[rt][ct] = __builtin_amdgcn_mfma_f32_16x16x32_f16(uf[ks], qf[rt][ks], an[rt][ct], 0, 0, 0);
                }
        }

        // ---- gate in registers: A^T tile is directly the 16x16x16 A-operand
        h4v ag[2][4];
#pragma unroll
        for (int rt = 0; rt < 2; ++rt)
#pragma unroll
            for (int ct = 0; ct < 4; ++ct)
#pragma unroll
                for (int r = 0; r < 4; ++r) {
                    const float mv = am[rt][ct][r];
                    const float nv = an[rt][ct][r];
                    const float sg = __builtin_amdgcn_rcpf(1.f + __expf(-mv));
                    ag[rt][ct][r] = (_Float16)(mv * sg * nv);
                }

        // ---- O += A V; V B-frags fully coalesced from fragment-ready layout
        const _Float16* vp = vb + (size_t)it * 8192;    // 16 chunks x 512 f16
#pragma unroll
        for (int p = 0; p < 2; ++p) {
            h8v vv[8];
#pragma unroll
            for (int dt = 0; dt < 8; ++dt)
                vv[dt] = *(const h8v*)(vp + (p * 8 + dt) * 512);
#pragma unroll
            for (int dt = 0; dt < 8; ++dt) {
                const h4v vlo = {vv[dt][0], vv[dt][1], vv[dt][2], vv[dt][3]};
                const h4v vhi = {vv[dt][4], vv[dt][5], vv[dt][6], vv[dt][7]};
#pragma unroll
                for (int rt = 0; rt < 2; ++rt) {
                    acc[rt][dt] = __builtin_amdgcn_mfma_f32_16x16x16f16(ag[rt][p * 2 + 0], vlo, acc[rt][dt], 0, 0, 0);
                    acc[rt][dt] = __builtin_amdgcn_mfma_f32_16x16x16f16(ag[rt][p * 2 + 1], vhi, acc[rt][dt], 0, 0, 0);
                }
            }
        }
    }

    // ---- epilogue: D[m=s][n=d], row = qq*4+r, col = m16
#pragma unroll
    for (int rt = 0; rt < 2; ++rt) {
#pragma unroll
        for (int r = 0; r < 4; ++r) {
            const int row = stile * BM + wave * 32 + rt * 16 + qq * 4 + r;
            float* op = Og + ((size_t)(b * H_ + h) * S_ + row) * D_;
#pragma unroll
            for (int dt = 0; dt < 8; ++dt)
                op[dt * 16 + m16] = acc[rt][dt][r];
        }
    }
}

extern "C" void kernel_launch(void* const* d_in, const int* in_sizes, int n_in,
                              void* d_out, int out_size, void* d_ws, size_t ws_size,
                              hipStream_t stream) {
    const float* Q = (const float*)d_in[0];
    const float* K = (const float*)d_in[1];
    const float* U = (const float*)d_in[2];
    const float* V = (const float*)d_in[3];
    float* out = (float*)d_out;

    _Float16* Kf = (_Float16*)d_ws;
    _Float16* Uf = Kf + (size_t)HK_ * FRAG_PER_KH;
    _Float16* Vf = Uf + (size_t)HK_ * FRAG_PER_KH;   // 6 MB total in d_ws

    prep<<<dim3(1536), dim3(256), 0, stream>>>(K, U, V, Kf, Uf, Vf);

    const int grid = (S_ / BM) * B_ * H_;   // 16 * 32 = 512 blocks
    flashmlp_kernel<<<dim3(grid), dim3(TPB), 0, stream>>>(Q, Kf, Uf, Vf, out);
}